// Round 10
// baseline (184.188 us; speedup 1.0000x reference)
//
#include <hip/hip_runtime.h>
#include <hip/hip_bf16.h>
#include <math.h>

typedef __bf16 bf16;
typedef __attribute__((ext_vector_type(8))) __bf16 bf16x8;
typedef __attribute__((ext_vector_type(4))) short s16x4;
typedef __attribute__((ext_vector_type(4))) float f32x4;

#define EMB 768
#define T_SEQ 1024
#define HEADS 12
#define HDIM 64

// ---------------- prep: W_attn / W_proj transpose+cvt only (x-convert fused into gemm1) ----------------
__global__ void prep_k(const float* __restrict__ Wa, bf16* __restrict__ Wta,
                       const float* __restrict__ Wp, bf16* __restrict__ Wtp) {
  __shared__ float tile[32][33];
  const int blk = blockIdx.x, tid = threadIdx.x;
  const float* in;
  bf16* out;
  int C, t;
  if (blk < 1728) { in = Wa; out = Wta; C = 3 * EMB; t = blk; }
  else            { in = Wp; out = Wtp; C = EMB;     t = blk - 1728; }
  const int R = EMB;
  const int c0 = (t % (C / 32)) * 32, r0 = (t / (C / 32)) * 32;
  const int tx = tid & 31, ty = tid >> 5;
  for (int i = ty; i < 32; i += 8)
    tile[i][tx] = in[(size_t)(r0 + i) * C + c0 + tx];
  __syncthreads();
  for (int i = ty; i < 32; i += 8)
    out[(size_t)(c0 + i) * R + r0 + tx] = (bf16)tile[tx][i];
}

// ---------------- GEMM: C[M][N] = A[M][K] @ Bt[N][K]^T + bias, BK=64 (2x32) ----------------
// R8 LDS XOR swizzle retained (verified): LDS[row][c8] = G[row][c8 ^ ((row>>1)&3)]
//  - B staging: global_load_lds with source-octet permute skk.
//  - R9: AF32 path stages A from fp32 source (float4 loads + cvt + ds_write_b128)
//    into BYTE-IDENTICAL LDS content: dest elem c*512 + lane*8 == row*32+(l&3)*8,
//    source octet = skk. Fuses the x fp32->bf16 pass into gemm1; read path and
//    MODE-1 (bf16 A via global_load_lds) unchanged.
template <int MODE, int NXT, bool AF32>
__global__ __launch_bounds__(256) void gemm_bt(
    const bf16* __restrict__ A, const float* __restrict__ A32,
    const bf16* __restrict__ Bt, const float* __restrict__ bias,
    bf16* __restrict__ Cb, float* __restrict__ Cf, int M, int N, int K) {
  __shared__ __align__(16) bf16 As0[128 * 32];
  __shared__ __align__(16) bf16 As1[128 * 32];
  __shared__ __align__(16) bf16 Bs0[128 * 32];
  __shared__ __align__(16) bf16 Bs1[128 * 32];
  const int lane = threadIdx.x & 63;
  const int wave = threadIdx.x >> 6;
  const int quad = lane >> 4, lc = lane & 15;

  // XCD-aware tile assignment (dispatch round-robins blockIdx % 8 across XCDs)
  const int xcd = blockIdx.x & 7;
  const int idx = blockIdx.x >> 3;           // 0 .. NXT*8-1 per XCD
  const int m0 = (xcd * 8 + (idx & 7)) * 128;
  const int n0 = (idx >> 3) * 128;           // x-outer: W-tile streams, A-tiles persist

  const int wm = (wave >> 1) * 64, wn = (wave & 1) * 64;
  const int srow = lane >> 2;
  const int skk = (((lane & 3) ^ ((lane >> 3) & 3))) * 8;   // swizzled source octet
  const int rq = (quad ^ ((lane >> 1) & 3)) * 8;            // swizzled read octet

  f32x4 zero = {0.f, 0.f, 0.f, 0.f};
  f32x4 acc[4][4];
#pragma unroll
  for (int i = 0; i < 4; ++i)
#pragma unroll
    for (int j = 0; j < 4; ++j) acc[i][j] = zero;

  for (int k0 = 0; k0 < K; k0 += 64) {
    __syncthreads();
#pragma unroll
    for (int c = wave; c < 8; c += 4) {
      const bf16* gB = Bt + (size_t)(n0 + c * 16 + srow) * K + k0 + skk;
      __builtin_amdgcn_global_load_lds((const __attribute__((address_space(1))) void*)gB,
                                       (__attribute__((address_space(3))) void*)(Bs0 + c * 512), 16, 0, 0);
      __builtin_amdgcn_global_load_lds((const __attribute__((address_space(1))) void*)(gB + 32),
                                       (__attribute__((address_space(3))) void*)(Bs1 + c * 512), 16, 0, 0);
      if constexpr (AF32) {
        const float* gA = A32 + (size_t)(m0 + c * 16 + srow) * K + k0 + skk;
        const float4 f0 = *(const float4*)(gA);
        const float4 f1 = *(const float4*)(gA + 4);
        const float4 f2 = *(const float4*)(gA + 32);
        const float4 f3 = *(const float4*)(gA + 36);
        bf16x8 v0, v1;
        v0[0] = (bf16)f0.x; v0[1] = (bf16)f0.y; v0[2] = (bf16)f0.z; v0[3] = (bf16)f0.w;
        v0[4] = (bf16)f1.x; v0[5] = (bf16)f1.y; v0[6] = (bf16)f1.z; v0[7] = (bf16)f1.w;
        v1[0] = (bf16)f2.x; v1[1] = (bf16)f2.y; v1[2] = (bf16)f2.z; v1[3] = (bf16)f2.w;
        v1[4] = (bf16)f3.x; v1[5] = (bf16)f3.y; v1[6] = (bf16)f3.z; v1[7] = (bf16)f3.w;
        *(bf16x8*)&As0[c * 512 + lane * 8] = v0;   // == row*32 + (lane&3)*8
        *(bf16x8*)&As1[c * 512 + lane * 8] = v1;
      } else {
        const bf16* gA = A + (size_t)(m0 + c * 16 + srow) * K + k0 + skk;
        __builtin_amdgcn_global_load_lds((const __attribute__((address_space(1))) void*)gA,
                                         (__attribute__((address_space(3))) void*)(As0 + c * 512), 16, 0, 0);
        __builtin_amdgcn_global_load_lds((const __attribute__((address_space(1))) void*)(gA + 32),
                                         (__attribute__((address_space(3))) void*)(As1 + c * 512), 16, 0, 0);
      }
    }
    __syncthreads();
    {
      bf16x8 af[4], bfr[4];
#pragma unroll
      for (int t = 0; t < 4; ++t) af[t] = *(const bf16x8*)&As0[(wm + t * 16 + lc) * 32 + rq];
#pragma unroll
      for (int t = 0; t < 4; ++t) bfr[t] = *(const bf16x8*)&Bs0[(wn + t * 16 + lc) * 32 + rq];
#pragma unroll
      for (int tm = 0; tm < 4; ++tm)
#pragma unroll
        for (int tn = 0; tn < 4; ++tn)
          acc[tm][tn] = __builtin_amdgcn_mfma_f32_16x16x32_bf16(af[tm], bfr[tn], acc[tm][tn], 0, 0, 0);
    }
    {
      bf16x8 af[4], bfr[4];
#pragma unroll
      for (int t = 0; t < 4; ++t) af[t] = *(const bf16x8*)&As1[(wm + t * 16 + lc) * 32 + rq];
#pragma unroll
      for (int t = 0; t < 4; ++t) bfr[t] = *(const bf16x8*)&Bs1[(wn + t * 16 + lc) * 32 + rq];
#pragma unroll
      for (int tm = 0; tm < 4; ++tm)
#pragma unroll
        for (int tn = 0; tn < 4; ++tn)
          acc[tm][tn] = __builtin_amdgcn_mfma_f32_16x16x32_bf16(af[tm], bfr[tn], acc[tm][tn], 0, 0, 0);
    }
  }

#pragma unroll
  for (int tm = 0; tm < 4; ++tm) {
#pragma unroll
    for (int tn = 0; tn < 4; ++tn) {
      const int col = n0 + wn + tn * 16 + lc;
      const float bv = bias[col];
#pragma unroll
      for (int r = 0; r < 4; ++r) {
        const int row = m0 + wm + tm * 16 + quad * 4 + r;
        const float v = acc[tm][tn][r] + bv;
        if (MODE == 0) Cb[(size_t)row * N + col] = (bf16)v;
        else           Cf[(size_t)row * N + col] = v;
      }
    }
  }
}

// ---------------- causal flash attention (R4 variant, best measured) ----------------
// qkv: [B*T][2304] rows (q|k|v); outb: [B*T][768]
//  - T14 async K/V register prefetch; __launch_bounds__(512,2) -> no spills.
//  - V transpose-staging bank-spread: key = 16w + (l>>2), d8 = (l&3)*8 + 32t.
//  - Q in registers (scaled at load); epilogue stages O through Ks.
__global__ __launch_bounds__(512, 2) void attn_k(const bf16* __restrict__ qkv,
                                                 bf16* __restrict__ outb) {
  __shared__ __align__(16) bf16 Ks[128][72];   // [key][d]; reused for O out
  __shared__ __align__(16) bf16 Vt[64][132];   // V^T [d][key]

  const int lane = threadIdx.x & 63;
  const int wave = threadIdx.x >> 6;           // 0..7, each owns 16 q rows
  const int quad = lane >> 4, lc = lane & 15;
  const int flat = blockIdx.x;
  const int bh = flat % (HEADS * 8);
  const int qt = 7 - flat / (HEADS * 8);
  const int h = bh % HEADS;
  const int b = bh / HEADS;
  const int q0 = qt * 128;
  const size_t rowB = (size_t)b * T_SEQ;
  const int hoff = h * HDIM;
  const int tid = threadIdx.x;
  const float C1 = 0.125f * 1.44269504f;       // 1/sqrt(64) * log2(e), folded into Q

  // staging coordinates
  const int kkey0 = tid >> 3;                  // K: key for t=0 chunk (+64 for t=1)
  const int ksd8 = (tid & 7) * 8;              // K: d offset
  const int vkey = wave * 16 + (lane >> 2);    // V: bank-spread mapping
  const int vd8base = (lane & 3) * 8;          // V: d base (+32 for t=1)
  const bf16* kbase = qkv + rowB * (size_t)(3 * EMB) + EMB + hoff;
  const bf16* vbase = qkv + rowB * (size_t)(3 * EMB) + 2 * EMB + hoff;

  // prefetch registers for K/V tile kt=0
  bf16x8 kreg[2], vreg[2];
#pragma unroll
  for (int t = 0; t < 2; ++t) {
    kreg[t] = *(const bf16x8*)(kbase + (size_t)(kkey0 + t * 64) * (3 * EMB) + ksd8);
    vreg[t] = *(const bf16x8*)(vbase + (size_t)vkey * (3 * EMB) + vd8base + t * 32);
  }

  // Q fragments straight to registers (loads overlap the K/V prefetch above)
  bf16x8 qfrag[2];
  {
    const bf16* qrow =
        qkv + (rowB + q0 + wave * 16 + lc) * (size_t)(3 * EMB) + hoff + quad * 8;
#pragma unroll
    for (int ks = 0; ks < 2; ++ks) {
      bf16x8 v = *(const bf16x8*)(qrow + ks * 32);
#pragma unroll
      for (int i = 0; i < 8; ++i) v[i] = (bf16)((float)v[i] * C1);
      qfrag[ks] = v;
    }
  }

  f32x4 zero = {0.f, 0.f, 0.f, 0.f};
  float l_run = 0.f;
  f32x4 o[4];  // O'[d][q]: col q=lc, row d=dt*16+quad*4+r
#pragma unroll
  for (int dt = 0; dt < 4; ++dt) o[dt] = zero;
  const int myq = q0 + wave * 16 + lc;

  for (int kt = 0; kt <= qt; ++kt) {
    const int kb = kt * 128;
    __syncthreads();
    // write prefetched K/V regs into LDS
#pragma unroll
    for (int t = 0; t < 2; ++t)
      *(bf16x8*)&Ks[kkey0 + t * 64][ksd8] = kreg[t];
#pragma unroll
    for (int t = 0; t < 2; ++t) {
      const int d8 = vd8base + t * 32;
#pragma unroll
      for (int i = 0; i < 8; ++i) Vt[d8 + i][vkey] = vreg[t][i];
    }
    __syncthreads();

    // issue next tile's global loads; they retire under this tile's compute
    if (kt < qt) {
      const size_t nb = (size_t)(kt + 1) * 128;
#pragma unroll
      for (int t = 0; t < 2; ++t) {
        kreg[t] = *(const bf16x8*)(kbase + (nb + kkey0 + t * 64) * (3 * EMB) + ksd8);
        vreg[t] = *(const bf16x8*)(vbase + (nb + vkey) * (3 * EMB) + vd8base + t * 32);
      }
    }

    f32x4 s[8];
#pragma unroll
    for (int j = 0; j < 8; ++j) s[j] = zero;
#pragma unroll
    for (int ks = 0; ks < 2; ++ks) {
      bf16x8 bq = qfrag[ks];
#pragma unroll
      for (int j = 0; j < 8; ++j) {
        bf16x8 ak = *(const bf16x8*)&Ks[j * 16 + lc][ks * 32 + quad * 8];
        s[j] = __builtin_amdgcn_mfma_f32_16x16x32_bf16(ak, bq, s[j], 0, 0, 0);
      }
    }

    s16x4 pf[8];
    const bool diag = (kt == qt);
    if (diag) {
#pragma unroll
      for (int j = 0; j < 8; ++j) {
#pragma unroll
        for (int r = 0; r < 4; ++r) {
          const bool masked = (kb + j * 16 + quad * 4 + r > myq);
          const float p = masked ? 0.f : exp2f(s[j][r]);
          l_run += p;
          pf[j][r] = __builtin_bit_cast(short, (bf16)p);
        }
      }
    } else {
#pragma unroll
      for (int j = 0; j < 8; ++j) {
#pragma unroll
        for (int r = 0; r < 4; ++r) {
          const float p = exp2f(s[j][r]);
          l_run += p;
          pf[j][r] = __builtin_bit_cast(short, (bf16)p);
        }
      }
    }

#pragma unroll
    for (int j = 0; j < 8; ++j) {
#pragma unroll
      for (int dt = 0; dt < 4; ++dt) {
        s16x4 av = *(const s16x4*)&Vt[dt * 16 + lc][j * 16 + quad * 4];
        o[dt] = __builtin_amdgcn_mfma_f32_16x16x16bf16_1k(av, pf[j], o[dt], 0, 0, 0);
      }
    }
  }

  l_run += __shfl_xor(l_run, 16);
  l_run += __shfl_xor(l_run, 32);
  const float inv = 1.0f / l_run;
  __syncthreads();
#pragma unroll
  for (int dt = 0; dt < 4; ++dt)
#pragma unroll
    for (int r = 0; r < 4; ++r)
      Ks[wave * 16 + lc][dt * 16 + quad * 4 + r] = (bf16)(o[dt][r] * inv);
  __syncthreads();
  for (int c = tid; c < 128 * 8; c += 512) {
    const int r = c >> 3, d8 = (c & 7) * 8;
    *(bf16x8*)(outb + (rowB + q0 + r) * EMB + hoff + d8) = *(const bf16x8*)&Ks[r][d8];
  }
}

// ---------------- launch ----------------
extern "C" void kernel_launch(void* const* d_in, const int* in_sizes, int n_in,
                              void* d_out, int out_size, void* d_ws, size_t ws_size,
                              hipStream_t stream) {
  const float* x = (const float*)d_in[0];
  const float* Wattn = (const float*)d_in[1];
  const float* battn = (const float*)d_in[2];
  const float* Wproj = (const float*)d_in[3];
  const float* bproj = (const float*)d_in[4];
  float* out = (float*)d_out;

  const int M = in_sizes[0] / EMB;  // 8192
  const int Bn = M / T_SEQ;         // 8

  bf16* ws = (bf16*)d_ws;
  bf16* Wt_attn = ws;                                   // [2304][768]
  bf16* Wt_proj = Wt_attn + (size_t)3 * EMB * EMB;      // [768][768]
  bf16* qkv = Wt_proj + (size_t)EMB * EMB;              // [M][2304]
  bf16* attnb = qkv + (size_t)M * 3 * EMB;              // [M][768]

  prep_k<<<1728 + 576, 256, 0, stream>>>(Wattn, Wt_attn, Wproj, Wt_proj);

  gemm_bt<0, 18, true><<<18 * 64, 256, 0, stream>>>(
      nullptr, x, Wt_attn, battn, qkv, nullptr, M, 3 * EMB, EMB);

  attn_k<<<dim3((T_SEQ / 128) * Bn * HEADS), 512, 0, stream>>>(qkv, attnb);

  gemm_bt<1, 6, false><<<6 * 64, 256, 0, stream>>>(
      attnb, nullptr, Wt_proj, bproj, nullptr, out, M, EMB, EMB);
}

// Round 12
// 174.466 us; speedup vs baseline: 1.0557x; 1.0557x over previous
//
#include <hip/hip_runtime.h>
#include <hip/hip_bf16.h>
#include <math.h>

typedef __bf16 bf16;
typedef __attribute__((ext_vector_type(8))) __bf16 bf16x8;
typedef __attribute__((ext_vector_type(4))) short s16x4;
typedef __attribute__((ext_vector_type(4))) float f32x4;

#define EMB 768
#define T_SEQ 1024
#define HEADS 12
#define HDIM 64

// ---------------- prep: W_attn / W_proj transpose+cvt only (x-convert fused into gemm1) ----------------
__global__ void prep_k(const float* __restrict__ Wa, bf16* __restrict__ Wta,
                       const float* __restrict__ Wp, bf16* __restrict__ Wtp) {
  __shared__ float tile[32][33];
  const int blk = blockIdx.x, tid = threadIdx.x;
  const float* in;
  bf16* out;
  int C, t;
  if (blk < 1728) { in = Wa; out = Wta; C = 3 * EMB; t = blk; }
  else            { in = Wp; out = Wtp; C = EMB;     t = blk - 1728; }
  const int R = EMB;
  const int c0 = (t % (C / 32)) * 32, r0 = (t / (C / 32)) * 32;
  const int tx = tid & 31, ty = tid >> 5;
  for (int i = ty; i < 32; i += 8)
    tile[i][tx] = in[(size_t)(r0 + i) * C + c0 + tx];
  __syncthreads();
  for (int i = ty; i < 32; i += 8)
    out[(size_t)(c0 + i) * R + r0 + tx] = (bf16)tile[tx][i];
}

// ---------------- GEMM: C[M][N] = A[M][K] @ Bt[N][K]^T + bias, BK=64 (2x32) ----------------
// R8 LDS XOR swizzle retained: LDS[row][c8] = G[row][c8 ^ ((row>>1)&3)], source
// octet permute skk for staging, read octet rq. Bank conflicts measured 0 (R9).
// R10/R11: AF32 path uses the async-STAGE split (G15, T14): fp32 A loads for
// tile k+1 are ISSUED right after barrier2 (start of the 32-MFMA phase, ~2000cy
// of cover) and converted+ds_written at the top of iteration k+1. R9's version
// issued-and-consumed between the two barriers -> ~600cy exposed/K-step -> 63us.
// VGPR: acc 64 + apf 32 + frags 16 + addr ~12 = ~124, same occupancy tier as 76
// (m69 tier bounds 64/128); no min-waves bound -> no forced spill.
template <int MODE, int NXT, bool AF32>
__global__ __launch_bounds__(256) void gemm_bt(
    const bf16* __restrict__ A, const float* __restrict__ A32,
    const bf16* __restrict__ Bt, const float* __restrict__ bias,
    bf16* __restrict__ Cb, float* __restrict__ Cf, int M, int N, int K) {
  __shared__ __align__(16) bf16 As0[128 * 32];
  __shared__ __align__(16) bf16 As1[128 * 32];
  __shared__ __align__(16) bf16 Bs0[128 * 32];
  __shared__ __align__(16) bf16 Bs1[128 * 32];
  const int lane = threadIdx.x & 63;
  const int wave = threadIdx.x >> 6;
  const int quad = lane >> 4, lc = lane & 15;

  // XCD-aware tile assignment (dispatch round-robins blockIdx % 8 across XCDs)
  const int xcd = blockIdx.x & 7;
  const int idx = blockIdx.x >> 3;           // 0 .. NXT*8-1 per XCD
  const int m0 = (xcd * 8 + (idx & 7)) * 128;
  const int n0 = (idx >> 3) * 128;           // x-outer: W-tile streams, A-tiles persist

  const int wm = (wave >> 1) * 64, wn = (wave & 1) * 64;
  const int srow = lane >> 2;
  const int skk = (((lane & 3) ^ ((lane >> 3) & 3))) * 8;   // swizzled source octet
  const int rq = (quad ^ ((lane >> 1) & 3)) * 8;            // swizzled read octet

  f32x4 zero = {0.f, 0.f, 0.f, 0.f};
  f32x4 acc[4][4];
#pragma unroll
  for (int i = 0; i < 4; ++i)
#pragma unroll
    for (int j = 0; j < 4; ++j) acc[i][j] = zero;

  // A fp32 prefetch registers (AF32): 2 c-chunks x {As0-half, As1-half} x 2 float4
  float4 apf[8];
  if constexpr (AF32) {
#pragma unroll
    for (int ci = 0; ci < 2; ++ci) {
      const float* gA = A32 + (size_t)(m0 + (wave + ci * 4) * 16 + srow) * K + skk;
      apf[ci * 4 + 0] = *(const float4*)(gA);
      apf[ci * 4 + 1] = *(const float4*)(gA + 4);
      apf[ci * 4 + 2] = *(const float4*)(gA + 32);
      apf[ci * 4 + 3] = *(const float4*)(gA + 36);
    }
  }

  for (int k0 = 0; k0 < K; k0 += 64) {
    __syncthreads();
    if constexpr (AF32) {
      // write-late: convert the prefetched fp32 regs and store (R9-verified indexing)
#pragma unroll
      for (int ci = 0; ci < 2; ++ci) {
        const int c = wave + ci * 4;
        bf16x8 v0, v1;
        v0[0] = (bf16)apf[ci * 4 + 0].x; v0[1] = (bf16)apf[ci * 4 + 0].y;
        v0[2] = (bf16)apf[ci * 4 + 0].z; v0[3] = (bf16)apf[ci * 4 + 0].w;
        v0[4] = (bf16)apf[ci * 4 + 1].x; v0[5] = (bf16)apf[ci * 4 + 1].y;
        v0[6] = (bf16)apf[ci * 4 + 1].z; v0[7] = (bf16)apf[ci * 4 + 1].w;
        v1[0] = (bf16)apf[ci * 4 + 2].x; v1[1] = (bf16)apf[ci * 4 + 2].y;
        v1[2] = (bf16)apf[ci * 4 + 2].z; v1[3] = (bf16)apf[ci * 4 + 2].w;
        v1[4] = (bf16)apf[ci * 4 + 3].x; v1[5] = (bf16)apf[ci * 4 + 3].y;
        v1[6] = (bf16)apf[ci * 4 + 3].z; v1[7] = (bf16)apf[ci * 4 + 3].w;
        *(bf16x8*)&As0[c * 512 + lane * 8] = v0;   // == row*32 + (lane&3)*8
        *(bf16x8*)&As1[c * 512 + lane * 8] = v1;
      }
    }
#pragma unroll
    for (int c = wave; c < 8; c += 4) {
      const bf16* gB = Bt + (size_t)(n0 + c * 16 + srow) * K + k0 + skk;
      __builtin_amdgcn_global_load_lds((const __attribute__((address_space(1))) void*)gB,
                                       (__attribute__((address_space(3))) void*)(Bs0 + c * 512), 16, 0, 0);
      __builtin_amdgcn_global_load_lds((const __attribute__((address_space(1))) void*)(gB + 32),
                                       (__attribute__((address_space(3))) void*)(Bs1 + c * 512), 16, 0, 0);
      if constexpr (!AF32) {
        const bf16* gA = A + (size_t)(m0 + c * 16 + srow) * K + k0 + skk;
        __builtin_amdgcn_global_load_lds((const __attribute__((address_space(1))) void*)gA,
                                         (__attribute__((address_space(3))) void*)(As0 + c * 512), 16, 0, 0);
        __builtin_amdgcn_global_load_lds((const __attribute__((address_space(1))) void*)(gA + 32),
                                         (__attribute__((address_space(3))) void*)(As1 + c * 512), 16, 0, 0);
      }
    }
    __syncthreads();
    // issue-early: next tile's A loads retire under the MFMA phase below
    if constexpr (AF32) {
      if (k0 + 64 < K) {
#pragma unroll
        for (int ci = 0; ci < 2; ++ci) {
          const float* gA =
              A32 + (size_t)(m0 + (wave + ci * 4) * 16 + srow) * K + (k0 + 64) + skk;
          apf[ci * 4 + 0] = *(const float4*)(gA);
          apf[ci * 4 + 1] = *(const float4*)(gA + 4);
          apf[ci * 4 + 2] = *(const float4*)(gA + 32);
          apf[ci * 4 + 3] = *(const float4*)(gA + 36);
        }
      }
    }
    {
      bf16x8 af[4], bfr[4];
#pragma unroll
      for (int t = 0; t < 4; ++t) af[t] = *(const bf16x8*)&As0[(wm + t * 16 + lc) * 32 + rq];
#pragma unroll
      for (int t = 0; t < 4; ++t) bfr[t] = *(const bf16x8*)&Bs0[(wn + t * 16 + lc) * 32 + rq];
#pragma unroll
      for (int tm = 0; tm < 4; ++tm)
#pragma unroll
        for (int tn = 0; tn < 4; ++tn)
          acc[tm][tn] = __builtin_amdgcn_mfma_f32_16x16x32_bf16(af[tm], bfr[tn], acc[tm][tn], 0, 0, 0);
    }
    {
      bf16x8 af[4], bfr[4];
#pragma unroll
      for (int t = 0; t < 4; ++t) af[t] = *(const bf16x8*)&As1[(wm + t * 16 + lc) * 32 + rq];
#pragma unroll
      for (int t = 0; t < 4; ++t) bfr[t] = *(const bf16x8*)&Bs1[(wn + t * 16 + lc) * 32 + rq];
#pragma unroll
      for (int tm = 0; tm < 4; ++tm)
#pragma unroll
        for (int tn = 0; tn < 4; ++tn)
          acc[tm][tn] = __builtin_amdgcn_mfma_f32_16x16x32_bf16(af[tm], bfr[tn], acc[tm][tn], 0, 0, 0);
    }
  }

#pragma unroll
  for (int tm = 0; tm < 4; ++tm) {
#pragma unroll
    for (int tn = 0; tn < 4; ++tn) {
      const int col = n0 + wn + tn * 16 + lc;
      const float bv = bias[col];
#pragma unroll
      for (int r = 0; r < 4; ++r) {
        const int row = m0 + wm + tm * 16 + quad * 4 + r;
        const float v = acc[tm][tn][r] + bv;
        if (MODE == 0) Cb[(size_t)row * N + col] = (bf16)v;
        else           Cf[(size_t)row * N + col] = v;
      }
    }
  }
}

// ---------------- causal flash attention (R4 variant, best measured) ----------------
// qkv: [B*T][2304] rows (q|k|v); outb: [B*T][768]
//  - T14 async K/V register prefetch; __launch_bounds__(512,2) -> no spills.
//  - V transpose-staging bank-spread: key = 16w + (l>>2), d8 = (l&3)*8 + 32t.
//  - Q in registers (scaled at load); epilogue stages O through Ks.
__global__ __launch_bounds__(512, 2) void attn_k(const bf16* __restrict__ qkv,
                                                 bf16* __restrict__ outb) {
  __shared__ __align__(16) bf16 Ks[128][72];   // [key][d]; reused for O out
  __shared__ __align__(16) bf16 Vt[64][132];   // V^T [d][key]

  const int lane = threadIdx.x & 63;
  const int wave = threadIdx.x >> 6;           // 0..7, each owns 16 q rows
  const int quad = lane >> 4, lc = lane & 15;
  const int flat = blockIdx.x;
  const int bh = flat % (HEADS * 8);
  const int qt = 7 - flat / (HEADS * 8);
  const int h = bh % HEADS;
  const int b = bh / HEADS;
  const int q0 = qt * 128;
  const size_t rowB = (size_t)b * T_SEQ;
  const int hoff = h * HDIM;
  const int tid = threadIdx.x;
  const float C1 = 0.125f * 1.44269504f;       // 1/sqrt(64) * log2(e), folded into Q

  // staging coordinates
  const int kkey0 = tid >> 3;                  // K: key for t=0 chunk (+64 for t=1)
  const int ksd8 = (tid & 7) * 8;              // K: d offset
  const int vkey = wave * 16 + (lane >> 2);    // V: bank-spread mapping
  const int vd8base = (lane & 3) * 8;          // V: d base (+32 for t=1)
  const bf16* kbase = qkv + rowB * (size_t)(3 * EMB) + EMB + hoff;
  const bf16* vbase = qkv + rowB * (size_t)(3 * EMB) + 2 * EMB + hoff;

  // prefetch registers for K/V tile kt=0
  bf16x8 kreg[2], vreg[2];
#pragma unroll
  for (int t = 0; t < 2; ++t) {
    kreg[t] = *(const bf16x8*)(kbase + (size_t)(kkey0 + t * 64) * (3 * EMB) + ksd8);
    vreg[t] = *(const bf16x8*)(vbase + (size_t)vkey * (3 * EMB) + vd8base + t * 32);
  }

  // Q fragments straight to registers (loads overlap the K/V prefetch above)
  bf16x8 qfrag[2];
  {
    const bf16* qrow =
        qkv + (rowB + q0 + wave * 16 + lc) * (size_t)(3 * EMB) + hoff + quad * 8;
#pragma unroll
    for (int ks = 0; ks < 2; ++ks) {
      bf16x8 v = *(const bf16x8*)(qrow + ks * 32);
#pragma unroll
      for (int i = 0; i < 8; ++i) v[i] = (bf16)((float)v[i] * C1);
      qfrag[ks] = v;
    }
  }

  f32x4 zero = {0.f, 0.f, 0.f, 0.f};
  float l_run = 0.f;
  f32x4 o[4];  // O'[d][q]: col q=lc, row d=dt*16+quad*4+r
#pragma unroll
  for (int dt = 0; dt < 4; ++dt) o[dt] = zero;
  const int myq = q0 + wave * 16 + lc;

  for (int kt = 0; kt <= qt; ++kt) {
    const int kb = kt * 128;
    __syncthreads();
    // write prefetched K/V regs into LDS
#pragma unroll
    for (int t = 0; t < 2; ++t)
      *(bf16x8*)&Ks[kkey0 + t * 64][ksd8] = kreg[t];
#pragma unroll
    for (int t = 0; t < 2; ++t) {
      const int d8 = vd8base + t * 32;
#pragma unroll
      for (int i = 0; i < 8; ++i) Vt[d8 + i][vkey] = vreg[t][i];
    }
    __syncthreads();

    // issue next tile's global loads; they retire under this tile's compute
    if (kt < qt) {
      const size_t nb = (size_t)(kt + 1) * 128;
#pragma unroll
      for (int t = 0; t < 2; ++t) {
        kreg[t] = *(const bf16x8*)(kbase + (nb + kkey0 + t * 64) * (3 * EMB) + ksd8);
        vreg[t] = *(const bf16x8*)(vbase + (nb + vkey) * (3 * EMB) + vd8base + t * 32);
      }
    }

    f32x4 s[8];
#pragma unroll
    for (int j = 0; j < 8; ++j) s[j] = zero;
#pragma unroll
    for (int ks = 0; ks < 2; ++ks) {
      bf16x8 bq = qfrag[ks];
#pragma unroll
      for (int j = 0; j < 8; ++j) {
        bf16x8 ak = *(const bf16x8*)&Ks[j * 16 + lc][ks * 32 + quad * 8];
        s[j] = __builtin_amdgcn_mfma_f32_16x16x32_bf16(ak, bq, s[j], 0, 0, 0);
      }
    }

    s16x4 pf[8];
    const bool diag = (kt == qt);
    if (diag) {
#pragma unroll
      for (int j = 0; j < 8; ++j) {
#pragma unroll
        for (int r = 0; r < 4; ++r) {
          const bool masked = (kb + j * 16 + quad * 4 + r > myq);
          const float p = masked ? 0.f : exp2f(s[j][r]);
          l_run += p;
          pf[j][r] = __builtin_bit_cast(short, (bf16)p);
        }
      }
    } else {
#pragma unroll
      for (int j = 0; j < 8; ++j) {
#pragma unroll
        for (int r = 0; r < 4; ++r) {
          const float p = exp2f(s[j][r]);
          l_run += p;
          pf[j][r] = __builtin_bit_cast(short, (bf16)p);
        }
      }
    }

#pragma unroll
    for (int j = 0; j < 8; ++j) {
#pragma unroll
      for (int dt = 0; dt < 4; ++dt) {
        s16x4 av = *(const s16x4*)&Vt[dt * 16 + lc][j * 16 + quad * 4];
        o[dt] = __builtin_amdgcn_mfma_f32_16x16x16bf16_1k(av, pf[j], o[dt], 0, 0, 0);
      }
    }
  }

  l_run += __shfl_xor(l_run, 16);
  l_run += __shfl_xor(l_run, 32);
  const float inv = 1.0f / l_run;
  __syncthreads();
#pragma unroll
  for (int dt = 0; dt < 4; ++dt)
#pragma unroll
    for (int r = 0; r < 4; ++r)
      Ks[wave * 16 + lc][dt * 16 + quad * 4 + r] = (bf16)(o[dt][r] * inv);
  __syncthreads();
  for (int c = tid; c < 128 * 8; c += 512) {
    const int r = c >> 3, d8 = (c & 7) * 8;
    *(bf16x8*)(outb + (rowB + q0 + r) * EMB + hoff + d8) = *(const bf16x8*)&Ks[r][d8];
  }
}

// ---------------- launch ----------------
extern "C" void kernel_launch(void* const* d_in, const int* in_sizes, int n_in,
                              void* d_out, int out_size, void* d_ws, size_t ws_size,
                              hipStream_t stream) {
  const float* x = (const float*)d_in[0];
  const float* Wattn = (const float*)d_in[1];
  const float* battn = (const float*)d_in[2];
  const float* Wproj = (const float*)d_in[3];
  const float* bproj = (const float*)d_in[4];
  float* out = (float*)d_out;

  const int M = in_sizes[0] / EMB;  // 8192
  const int Bn = M / T_SEQ;         // 8

  bf16* ws = (bf16*)d_ws;
  bf16* Wt_attn = ws;                                   // [2304][768]
  bf16* Wt_proj = Wt_attn + (size_t)3 * EMB * EMB;      // [768][768]
  bf16* qkv = Wt_proj + (size_t)EMB * EMB;              // [M][2304]
  bf16* attnb = qkv + (size_t)M * 3 * EMB;              // [M][768]

  prep_k<<<1728 + 576, 256, 0, stream>>>(Wattn, Wt_attn, Wproj, Wt_proj);

  gemm_bt<0, 18, true><<<18 * 64, 256, 0, stream>>>(
      nullptr, x, Wt_attn, battn, qkv, nullptr, M, 3 * EMB, EMB);

  attn_k<<<dim3((T_SEQ / 128) * Bn * HEADS), 512, 0, stream>>>(qkv, attnb);

  gemm_bt<1, 6, false><<<6 * 64, 256, 0, stream>>>(
      attnb, nullptr, Wt_proj, bproj, nullptr, out, M, EMB, EMB);
}